// Round 9
// baseline (446.173 us; speedup 1.0000x reference)
//
#include <hip/hip_runtime.h>
#include <hip/hip_bf16.h>

// Biattention: x:[8,2048,1024] f32, mask:[8,2048] i32
// out = concat([x, c, x+c, x-c, x*c], -1) where c = softmax(mask(x x^T)) x
//
// R9: k_context = R7-EXACT (best measured: 168us, 4-phase forced-drain).
// k_scores: R7's proven 4-phase skeleton ported to 128^2/BK=64 (NT=48):
// same staging ladder (p0/p1 -> kt+1 kk1, p2/p3 -> kt+2 kk0), same vmcnt(4)
// boundary / vmcnt(0) tail, per-phase {ds_read+STG -> bar -> lgkm0+schedbar ->
// setprio -> 8 MFMA -> bar}. T2 swizzle unchanged (verified 0 conflicts).

typedef __attribute__((ext_vector_type(8))) __bf16 bf16x8;
typedef __attribute__((ext_vector_type(4))) float f32x4;

#define SEQ 2048
#define DIM 1024
#define NBATCH 8

__device__ __forceinline__ unsigned short f2bf(float f) {
  union { __hip_bfloat16 h; unsigned short u; } cv;
  cv.h = __float2bfloat16(f);
  return cv.u;
}
__device__ __forceinline__ float bf2f(unsigned short u) {
  union { __hip_bfloat16 h; unsigned short u; } cv;
  cv.u = u;
  return __bfloat162float(cv.h);
}

__device__ __forceinline__ void load16(const void* g, void* l) {
  __builtin_amdgcn_global_load_lds(
      (const __attribute__((address_space(1))) unsigned int*)g,
      (__attribute__((address_space(3))) unsigned int*)l, 16, 0, 0);
}

// ---------------- K1: convert + transpose ----------------
__global__ __launch_bounds__(256) void k_prep(
    const float* __restrict__ x, unsigned short* __restrict__ xh,
    unsigned short* __restrict__ xl, unsigned short* __restrict__ xT) {
  __shared__ unsigned short tile[32][33];
  int b = blockIdx.z;
  int s0 = blockIdx.x * 32;
  int d0 = blockIdx.y * 32;
  int t = threadIdx.x;
  int r = t >> 3;
  int c4 = (t & 7) * 4;

  long src = (long)(b * SEQ + s0 + r) * DIM + d0 + c4;
  float4 v = *(const float4*)(x + src);
  float vv[4] = {v.x, v.y, v.z, v.w};
  unsigned short hu[4], lu[4];
#pragma unroll
  for (int j = 0; j < 4; ++j) {
    hu[j] = f2bf(vv[j]);
    float hf = bf2f(hu[j]);
    lu[j] = f2bf(vv[j] - hf);
    tile[r][c4 + j] = hu[j];
  }
  *(ushort4*)(xh + src) = make_ushort4(hu[0], hu[1], hu[2], hu[3]);
  *(ushort4*)(xl + src) = make_ushort4(lu[0], lu[1], lu[2], lu[3]);
  __syncthreads();
  unsigned short tv[4];
#pragma unroll
  for (int j = 0; j < 4; ++j) tv[j] = tile[c4 + j][r];
  long dst = (long)(b * DIM + d0 + r) * SEQ + s0 + c4;
  *(ushort4*)(xT + dst) = make_ushort4(tv[0], tv[1], tv[2], tv[3]);
}

// ---------------- K2: scores GEMM (128^2, BK=64, 4-phase, symmetric) ----------------
// LDS per op: [2 buf][2 kk][128 R][32] ushorts = 32KB; A+B = 64KB -> 2 blocks/CU.
#define NT_SC 48
__global__ __launch_bounds__(256) void k_scores(
    const unsigned short* __restrict__ xh, const unsigned short* __restrict__ xl,
    float* __restrict__ S) {
  __shared__ unsigned short As[2 * 8192];
  __shared__ unsigned short Bs[2 * 8192];
  int p = blockIdx.x + 136 * blockIdx.z;   // 0..1087
  int b = p & 7;                            // one batch per XCD (T1)
  int t = p >> 3;                           // tri-index 0..135
  int bm = 0, rem = 16;
  while (t >= rem) { t -= rem; ++bm; --rem; }
  int bn = bm + t;
  int m0 = bm * 128;
  int n0 = bn * 128;
  const unsigned short* xh_b = xh + (long)b * SEQ * DIM;
  const unsigned short* xl_b = xl + (long)b * SEQ * DIM;
  float* S_b = S + (long)b * SEQ * SEQ;

  int tid = threadIdx.x;
  int w = tid >> 6, lane = tid & 63;
  int wr = w >> 1, wc = w & 1;
  int l15 = lane & 15, lhi = lane >> 4;

  // staging constants: per kk-half per op 512 chunks; 2 per thread
  int cbase0 = w * 64, cbase1 = 256 + w * 64;
  int c0 = cbase0 + lane, c1 = cbase1 + lane;
  int row0 = c0 >> 2, row1 = c1 >> 2;
  long aoff0 = (long)(m0 + row0) * DIM + ((c0 & 3) ^ ((row0 >> 1) & 3)) * 8;
  long aoff1 = (long)(m0 + row1) * DIM + ((c1 & 3) ^ ((row1 >> 1) & 3)) * 8;
  long boff0 = (long)(n0 + row0) * DIM + ((c0 & 3) ^ ((row0 >> 1) & 3)) * 8;
  long boff1 = (long)(n0 + row1) * DIM + ((c1 & 3) ^ ((row1 >> 1) & 3)) * 8;
  int ldg0 = cbase0 * 8, ldg1 = cbase1 * 8;

// tile KT covers k [KT*64, KT*64+64); pass = KT>>4 (16 tiles per 1024-pass)
#define SSTG_A(KT, KK, BUF)                                                  \
  {                                                                          \
    int pp_ = (KT) >> 4;                                                     \
    int kb_ = ((KT) & 15) * 64 + (KK) * 32;                                  \
    const unsigned short* s_ = (pp_ == 2) ? xl_b : xh_b;                     \
    load16(s_ + aoff0 + kb_, &As[(BUF) * 8192 + (KK) * 4096 + ldg0]);        \
    load16(s_ + aoff1 + kb_, &As[(BUF) * 8192 + (KK) * 4096 + ldg1]);        \
  }
#define SSTG_B(KT, KK, BUF)                                                  \
  {                                                                          \
    int pp_ = (KT) >> 4;                                                     \
    int kb_ = ((KT) & 15) * 64 + (KK) * 32;                                  \
    const unsigned short* s_ = (pp_ == 1) ? xl_b : xh_b;                     \
    load16(s_ + boff0 + kb_, &Bs[(BUF) * 8192 + (KK) * 4096 + ldg0]);        \
    load16(s_ + boff1 + kb_, &Bs[(BUF) * 8192 + (KK) * 4096 + ldg1]);        \
  }

  // fragment-read constants (slot XOR is per-thread constant)
  int swr = (lhi ^ ((l15 >> 1) & 3)) * 8;
  int arow = (wr * 64 + l15) * 32;
  int brow = (wc * 64 + l15) * 32;

#define SRD_BG(BUF, KK)                                                      \
  _Pragma("unroll") for (int n = 0; n < 4; ++n)                              \
      bg[n] = *(const bf16x8*)&Bs[(BUF) * 8192 + (KK) * 4096 + brow + n * 512 + swr];
#define SRD_AF(BUF, KK, MH)                                                  \
  _Pragma("unroll") for (int m = 0; m < 2; ++m)                              \
      af[m] = *(const bf16x8*)&As[(BUF) * 8192 + (KK) * 4096 + arow +        \
                                  ((MH) * 2 + m) * 512 + swr];
#define SDO(MH)                                                              \
  _Pragma("unroll") for (int m = 0; m < 2; ++m)                              \
      _Pragma("unroll") for (int n = 0; n < 4; ++n)                          \
          acc[(MH) * 2 + m][n] = __builtin_amdgcn_mfma_f32_16x16x32_bf16(    \
              af[m], bg[n], acc[(MH) * 2 + m][n], 0, 0, 0);
#define SPH(MH)                                                              \
  __builtin_amdgcn_s_barrier();                                              \
  asm volatile("s_waitcnt lgkmcnt(0)" ::: "memory");                         \
  __builtin_amdgcn_sched_barrier(0);                                         \
  __builtin_amdgcn_s_setprio(1);                                             \
  SDO(MH);                                                                   \
  __builtin_amdgcn_s_setprio(0);                                             \
  __builtin_amdgcn_sched_barrier(0);

  f32x4 acc[4][4];
#pragma unroll
  for (int m = 0; m < 4; ++m)
#pragma unroll
    for (int n = 0; n < 4; ++n)
#pragma unroll
      for (int j = 0; j < 4; ++j) acc[m][n][j] = 0.0f;

  // prologue: kt0 full (8) + kt1-kk0 (4) in flight; drain kt0 -> vmcnt(4)
  SSTG_A(0, 0, 0); SSTG_B(0, 0, 0);
  SSTG_A(0, 1, 0); SSTG_B(0, 1, 0);
  SSTG_A(1, 0, 1); SSTG_B(1, 0, 1);
  asm volatile("s_waitcnt vmcnt(4)" ::: "memory");
  __builtin_amdgcn_s_barrier();

  for (int kt = 0; kt < NT_SC; ++kt) {
    int c = kt & 1, o = c ^ 1;
    bf16x8 af[2], bg[4];
    // p0: kk0, m01
    SRD_AF(c, 0, 0); SRD_BG(c, 0);
    if (kt + 1 < NT_SC) SSTG_A(kt + 1, 1, o);
    SPH(0);
    __builtin_amdgcn_s_barrier();
    // p1: kk0, m23 (bg persists)
    SRD_AF(c, 0, 1);
    if (kt + 1 < NT_SC) SSTG_B(kt + 1, 1, o);
    SPH(1);
    __builtin_amdgcn_s_barrier();
    // p2: kk1, m01
    SRD_AF(c, 1, 0); SRD_BG(c, 1);
    if (kt + 2 < NT_SC) SSTG_A(kt + 2, 0, c);
    SPH(0);
    __builtin_amdgcn_s_barrier();
    // p3: kk1, m23
    SRD_AF(c, 1, 1);
    if (kt + 2 < NT_SC) SSTG_B(kt + 2, 0, c);
    SPH(1);
    if (kt < NT_SC - 2) {
      asm volatile("s_waitcnt vmcnt(4)" ::: "memory");
    } else if (kt == NT_SC - 2) {
      asm volatile("s_waitcnt vmcnt(0)" ::: "memory");
    }
    __builtin_amdgcn_s_barrier();
  }

  // epilogue (R5-exact layout): normal + transposed symmetric write
#pragma unroll
  for (int m = 0; m < 4; ++m)
#pragma unroll
    for (int n = 0; n < 4; ++n)
#pragma unroll
      for (int j = 0; j < 4; ++j) {
        int r = m0 + wr * 64 + m * 16 + lhi * 4 + j;
        int c = n0 + wc * 64 + n * 16 + l15;
        S_b[(long)r * SEQ + c] = acc[m][n][j];
      }
  if (bm != bn) {
#pragma unroll
    for (int m = 0; m < 4; ++m)
#pragma unroll
      for (int n = 0; n < 4; ++n) {
        int r0 = m0 + wr * 64 + m * 16 + lhi * 4;
        int c = n0 + wc * 64 + n * 16 + l15;
        *(f32x4*)&S_b[(long)c * SEQ + r0] = acc[m][n];
      }
  }
}

// ---------------- K3: masked softmax, wave per row ----------------
__global__ __launch_bounds__(256) void k_softmax(
    const float* __restrict__ S, const int* __restrict__ mask,
    unsigned short* __restrict__ P) {
  int w = threadIdx.x >> 6, lane = threadIdx.x & 63;
  long row = (long)blockIdx.x * 4 + w;
  int b = (int)(row >> 11);
  const float* Sp = S + row * SEQ;
  const int* mp = mask + b * SEQ;
  unsigned short* Pp = P + row * SEQ;

  float sv[32];
  float mx = -__builtin_inff();
#pragma unroll
  for (int ci = 0; ci < 8; ++ci) {
    int col = ci * 256 + lane * 4;
    float4 v = *(const float4*)(Sp + col);
    int4 mk = *(const int4*)(mp + col);
    sv[ci * 4 + 0] = mk.x ? v.x : -__builtin_inff();
    sv[ci * 4 + 1] = mk.y ? v.y : -__builtin_inff();
    sv[ci * 4 + 2] = mk.z ? v.z : -__builtin_inff();
    sv[ci * 4 + 3] = mk.w ? v.w : -__builtin_inff();
    mx = fmaxf(mx, fmaxf(fmaxf(sv[ci * 4 + 0], sv[ci * 4 + 1]),
                         fmaxf(sv[ci * 4 + 2], sv[ci * 4 + 3])));
  }
#pragma unroll
  for (int off = 32; off; off >>= 1) mx = fmaxf(mx, __shfl_xor(mx, off));
  float pv[32];
  float sum = 0.0f;
#pragma unroll
  for (int i = 0; i < 32; ++i) {
    pv[i] = expf(sv[i] - mx);
    sum += pv[i];
  }
#pragma unroll
  for (int off = 32; off; off >>= 1) sum += __shfl_xor(sum, off);
  float inv = 1.0f / sum;
#pragma unroll
  for (int ci = 0; ci < 8; ++ci) {
    int col = ci * 256 + lane * 4;
    *(ushort4*)(Pp + col) = make_ushort4(
        f2bf(pv[ci * 4 + 0] * inv), f2bf(pv[ci * 4 + 1] * inv),
        f2bf(pv[ci * 4 + 2] * inv), f2bf(pv[ci * 4 + 3] * inv));
  }
}

// ---------------- K4: context GEMM 256^2 BK=64, 4-phase (R7-EXACT) ----------------
#define NT_CTX 32
__global__ __launch_bounds__(512, 2) void k_context(
    const unsigned short* __restrict__ P, const unsigned short* __restrict__ xT,
    const float* __restrict__ x, float* __restrict__ out) {
  __shared__ unsigned short As[2 * 16384];  // 64 KB
  __shared__ unsigned short Bs[2 * 16384];  // 64 KB
  int p = blockIdx.x;            // 0..255
  int b = p & 7;                 // one batch per XCD (T1)
  int q = p >> 3;                // 0..31
  int n0 = (q & 3) * 256;        // d cols
  int m0 = (q >> 2) * 256;       // q rows
  const unsigned short* A_b = P + (long)b * SEQ * SEQ;
  const unsigned short* B_b = xT + (long)b * DIM * SEQ;

  int tid = threadIdx.x;
  int w = tid >> 6, lane = tid & 63;
  int wr = w >> 2, wc = w & 3;          // 2M x 4N waves; per-wave 128x64
  int l15 = lane & 15, lhi = lane >> 4;

  int c0 = w * 128 + lane, c1 = w * 128 + 64 + lane;
  int R0 = c0 >> 2, R1 = c1 >> 2;
  int sw0 = ((c0 & 3) ^ ((R0 >> 1) & 3)) * 8;
  int sw1 = ((c1 & 3) ^ ((R1 >> 1) & 3)) * 8;
  const unsigned short* PA0 = A_b + (long)(m0 + R0) * SEQ + sw0;
  const unsigned short* PA1 = A_b + (long)(m0 + R1) * SEQ + sw1;
  const unsigned short* PB0 = B_b + (long)(n0 + R0) * SEQ + sw0;
  const unsigned short* PB1 = B_b + (long)(n0 + R1) * SEQ + sw1;
  int ldg0 = (w * 128) * 8;
  int ldg1 = (w * 128 + 64) * 8;

#define STG_A(KT, KK, BUF)                                              \
  {                                                                     \
    load16(PA0 + (KT) * 64 + (KK) * 32, &As[(BUF)*16384 + (KK)*8192 + ldg0]); \
    load16(PA1 + (KT) * 64 + (KK) * 32, &As[(BUF)*16384 + (KK)*8192 + ldg1]); \
  }
#define STG_B(KT, KK, BUF)                                              \
  {                                                                     \
    load16(PB0 + (KT) * 64 + (KK) * 32, &Bs[(BUF)*16384 + (KK)*8192 + ldg0]); \
    load16(PB1 + (KT) * 64 + (KK) * 32, &Bs[(BUF)*16384 + (KK)*8192 + ldg1]); \
  }

  int swr = (lhi ^ ((l15 >> 1) & 3)) * 8;
  int arow = (wr * 128 + l15) * 32;
  int brow = (wc * 64 + l15) * 32;

#define RD_BG(BUF, KK)                                                        \
  _Pragma("unroll") for (int n = 0; n < 4; ++n)                               \
      bg[n] = *(const bf16x8*)&Bs[(BUF)*16384 + (KK)*8192 + brow + n * 512 + swr];
#define RD_AF(BUF, KK, MB)                                                    \
  _Pragma("unroll") for (int m = 0; m < 4; ++m)                               \
      af[m] = *(const bf16x8*)&As[(BUF)*16384 + (KK)*8192 + arow + ((MB)*4 + m) * 512 + swr];
#define DO_MFMA(MB)                                                           \
  _Pragma("unroll") for (int m = 0; m < 4; ++m)                               \
      _Pragma("unroll") for (int n = 0; n < 4; ++n)                           \
          acc[(MB)*4 + m][n] = __builtin_amdgcn_mfma_f32_16x16x32_bf16(       \
              bg[n], af[m], acc[(MB)*4 + m][n], 0, 0, 0);
#define PH_SYNC_MFMA(MB)                                                      \
  __builtin_amdgcn_s_barrier();                                               \
  asm volatile("s_waitcnt lgkmcnt(0)" ::: "memory");                          \
  __builtin_amdgcn_sched_barrier(0);                                          \
  __builtin_amdgcn_s_setprio(1);                                              \
  DO_MFMA(MB);                                                                \
  __builtin_amdgcn_s_setprio(0);                                              \
  __builtin_amdgcn_sched_barrier(0);

  f32x4 acc[8][4];
#pragma unroll
  for (int m = 0; m < 8; ++m)
#pragma unroll
    for (int n = 0; n < 4; ++n)
#pragma unroll
      for (int j = 0; j < 4; ++j) acc[m][n][j] = 0.0f;

  // prologue: kt0 full (8 loads) + kt1 kk0 (4 loads); drain kt0 -> vmcnt(4)
  STG_A(0, 0, 0); STG_B(0, 0, 0);
  STG_A(0, 1, 0); STG_B(0, 1, 0);
  STG_A(1, 0, 1); STG_B(1, 0, 1);
  asm volatile("s_waitcnt vmcnt(4)" ::: "memory");
  __builtin_amdgcn_s_barrier();

  for (int kt = 0; kt < NT_CTX; ++kt) {
    int c = kt & 1, o = c ^ 1;
    bf16x8 af[4], bg[4];
    // phase 0: kk0, m0-3 (+bg kk0)
    RD_AF(c, 0, 0); RD_BG(c, 0);
    if (kt + 1 < NT_CTX) STG_A(kt + 1, 1, o);
    PH_SYNC_MFMA(0);
    __builtin_amdgcn_s_barrier();
    // phase 1: kk0, m4-7 (bg kept in regs)
    RD_AF(c, 0, 1);
    if (kt + 1 < NT_CTX) STG_B(kt + 1, 1, o);
    PH_SYNC_MFMA(1);
    __builtin_amdgcn_s_barrier();
    // phase 2: kk1, m0-3 (+bg kk1)
    RD_AF(c, 1, 0); RD_BG(c, 1);
    if (kt + 2 < NT_CTX) STG_A(kt + 2, 0, c);
    PH_SYNC_MFMA(0);
    __builtin_amdgcn_s_barrier();
    // phase 3: kk1, m4-7
    RD_AF(c, 1, 1);
    if (kt + 2 < NT_CTX) STG_B(kt + 2, 0, c);
    PH_SYNC_MFMA(1);
    if (kt < NT_CTX - 2) {
      asm volatile("s_waitcnt vmcnt(4)" ::: "memory");
    } else if (kt == NT_CTX - 2) {
      asm volatile("s_waitcnt vmcnt(0)" ::: "memory");
    }
    __builtin_amdgcn_s_barrier();
  }

  // epilogue: swapped-operand C layout -> thread holds 4 consecutive d (f32x4)
  const float* x_b = x + (long)b * SEQ * DIM;
  float* out_b = out + (long)b * SEQ * (5 * DIM);
#pragma unroll
  for (int m = 0; m < 8; ++m)
#pragma unroll
    for (int n = 0; n < 4; ++n) {
      int qi = m0 + wr * 128 + m * 16 + l15;      // col index = q
      int d = n0 + wc * 64 + n * 16 + lhi * 4;    // row index = d (4 consec)
      f32x4 c4 = acc[m][n];
      f32x4 xv = *(const f32x4*)&x_b[(long)qi * DIM + d];
      long base = (long)qi * (5 * DIM) + d;
      *(f32x4*)&out_b[base] = xv;
      *(f32x4*)&out_b[base + DIM] = c4;
      *(f32x4*)&out_b[base + 2 * DIM] = xv + c4;
      *(f32x4*)&out_b[base + 3 * DIM] = xv - c4;
      *(f32x4*)&out_b[base + 4 * DIM] = xv * c4;
    }
}

extern "C" void kernel_launch(void* const* d_in, const int* in_sizes, int n_in,
                              void* d_out, int out_size, void* d_ws, size_t ws_size,
                              hipStream_t stream) {
  const float* x = (const float*)d_in[0];
  const int* mask = (const int*)d_in[1];
  float* out = (float*)d_out;
  char* ws = (char*)d_ws;

  const size_t HB = (size_t)NBATCH * SEQ * DIM * 2;
  unsigned short* xh = (unsigned short*)ws;
  unsigned short* xl = (unsigned short*)(ws + HB);
  unsigned short* xT = (unsigned short*)(ws + 2 * HB);
  unsigned short* P = (unsigned short*)(ws + 3 * HB);
  const size_t PB = (size_t)NBATCH * SEQ * SEQ * 2;
  const size_t SB = (size_t)NBATCH * SEQ * SEQ * 4;
  float* S;
  if (ws_size >= 3 * HB + PB + SB) {
    S = (float*)(ws + 3 * HB + PB);
  } else {
    S = (float*)d_out;  // S dead before K4 writes out
  }

  k_prep<<<dim3(SEQ / 32, DIM / 32, NBATCH), 256, 0, stream>>>(x, xh, xl, xT);
  k_scores<<<dim3(136, 1, NBATCH), 256, 0, stream>>>(xh, xl, S);
  k_softmax<<<NBATCH * SEQ / 4, 256, 0, stream>>>(S, mask, P);
  k_context<<<dim3(256, 1, 1), 512, 0, stream>>>(P, xT, x, out);
}

// Round 10
// 400.324 us; speedup vs baseline: 1.1145x; 1.1145x over previous
//
#include <hip/hip_runtime.h>
#include <hip/hip_bf16.h>

// Biattention: x:[8,2048,1024] f32, mask:[8,2048] i32
// out = concat([x, c, x+c, x-c, x*c], -1) where c = softmax(mask(x x^T)) x
//
// R10: scores = R5-exact (176us best). context = R7's phase-disciplined
// schedule at 2 phases/tile (32 MFMA per phase, 5 barriers/tile vs 9):
// same staging ladder + vmcnt(4)/(0) invariants as R7, coarser phases.
// Regime map measured R8/R9: phase discipline pays only at 256^2/8 waves;
// 128^2/4-wave scores wants compiler-scheduled d3.

typedef __attribute__((ext_vector_type(8))) __bf16 bf16x8;
typedef __attribute__((ext_vector_type(4))) float f32x4;

#define SEQ 2048
#define DIM 1024
#define NBATCH 8
#define BK 32

__device__ __forceinline__ unsigned short f2bf(float f) {
  union { __hip_bfloat16 h; unsigned short u; } cv;
  cv.h = __float2bfloat16(f);
  return cv.u;
}
__device__ __forceinline__ float bf2f(unsigned short u) {
  union { __hip_bfloat16 h; unsigned short u; } cv;
  cv.u = u;
  return __bfloat162float(cv.h);
}

__device__ __forceinline__ void load16(const void* g, void* l) {
  __builtin_amdgcn_global_load_lds(
      (const __attribute__((address_space(1))) unsigned int*)g,
      (__attribute__((address_space(3))) unsigned int*)l, 16, 0, 0);
}

// ---------------- K1: convert + transpose ----------------
__global__ __launch_bounds__(256) void k_prep(
    const float* __restrict__ x, unsigned short* __restrict__ xh,
    unsigned short* __restrict__ xl, unsigned short* __restrict__ xT) {
  __shared__ unsigned short tile[32][33];
  int b = blockIdx.z;
  int s0 = blockIdx.x * 32;
  int d0 = blockIdx.y * 32;
  int t = threadIdx.x;
  int r = t >> 3;
  int c4 = (t & 7) * 4;

  long src = (long)(b * SEQ + s0 + r) * DIM + d0 + c4;
  float4 v = *(const float4*)(x + src);
  float vv[4] = {v.x, v.y, v.z, v.w};
  unsigned short hu[4], lu[4];
#pragma unroll
  for (int j = 0; j < 4; ++j) {
    hu[j] = f2bf(vv[j]);
    float hf = bf2f(hu[j]);
    lu[j] = f2bf(vv[j] - hf);
    tile[r][c4 + j] = hu[j];
  }
  *(ushort4*)(xh + src) = make_ushort4(hu[0], hu[1], hu[2], hu[3]);
  *(ushort4*)(xl + src) = make_ushort4(lu[0], lu[1], lu[2], lu[3]);
  __syncthreads();
  unsigned short tv[4];
#pragma unroll
  for (int j = 0; j < 4; ++j) tv[j] = tile[c4 + j][r];
  long dst = (long)(b * DIM + d0 + r) * SEQ + s0 + c4;
  *(ushort4*)(xT + dst) = make_ushort4(tv[0], tv[1], tv[2], tv[3]);
}

// shared compute macro (R5-exact, used by k_scores)
#define COMPUTE_TILE(ARR_A, ARR_B, BUF)                                     \
  {                                                                         \
    bf16x8 af[4], bg[4];                                                    \
    _Pragma("unroll") for (int m = 0; m < 4; ++m) {                         \
      int R = wr * 64 + m * 16 + l15;                                       \
      af[m] = *(const bf16x8*)&ARR_A[BUF][R * BK + ((lhi ^ ((R >> 1) & 3)) * 8)]; \
    }                                                                       \
    _Pragma("unroll") for (int n = 0; n < 4; ++n) {                         \
      int R = wc * 64 + n * 16 + l15;                                       \
      bg[n] = *(const bf16x8*)&ARR_B[BUF][R * BK + ((lhi ^ ((R >> 1) & 3)) * 8)]; \
    }                                                                       \
    _Pragma("unroll") for (int m = 0; m < 4; ++m)                           \
      _Pragma("unroll") for (int n = 0; n < 4; ++n)                         \
        acc[m][n] = __builtin_amdgcn_mfma_f32_16x16x32_bf16(af[m], bg[n], acc[m][n], 0, 0, 0); \
  }

// ---------------- K2: scores GEMM (R5-exact: 128^2, split-bf16, symmetric, d3) ----------------
#define NT_SC 96
__global__ __launch_bounds__(256) void k_scores(
    const unsigned short* __restrict__ xh, const unsigned short* __restrict__ xl,
    float* __restrict__ S) {
  __shared__ unsigned short As[3][128 * BK];
  __shared__ unsigned short Bs[3][128 * BK];
  int p = blockIdx.x + 136 * blockIdx.z;   // 0..1087
  int b = p & 7;                            // one batch per XCD
  int t = p >> 3;                           // tri-index 0..135
  int bm = 0, rem = 16;
  while (t >= rem) { t -= rem; ++bm; --rem; }
  int bn = bm + t;
  int m0 = bm * 128;
  int n0 = bn * 128;
  const unsigned short* xh_b = xh + (long)b * SEQ * DIM;
  const unsigned short* xl_b = xl + (long)b * SEQ * DIM;
  float* S_b = S + (long)b * SEQ * SEQ;

  int tid = threadIdx.x;
  int w = tid >> 6, lane = tid & 63;
  int wr = w >> 1, wc = w & 1;
  int l15 = lane & 15, lhi = lane >> 4;

  int cbase0 = w * 64, cbase1 = 256 + w * 64;
  int c0 = cbase0 + lane, c1 = cbase1 + lane;
  int row0 = c0 >> 2, row1 = c1 >> 2;
  long aoff0 = (long)(m0 + row0) * DIM + ((c0 & 3) ^ ((row0 >> 1) & 3)) * 8;
  long aoff1 = (long)(m0 + row1) * DIM + ((c1 & 3) ^ ((row1 >> 1) & 3)) * 8;
  long boff0 = (long)(n0 + row0) * DIM + ((c0 & 3) ^ ((row0 >> 1) & 3)) * 8;
  long boff1 = (long)(n0 + row1) * DIM + ((c1 & 3) ^ ((row1 >> 1) & 3)) * 8;

#define STAGE_SC(KT, BUF)                                                   \
  {                                                                         \
    int k0_ = (KT) * BK;                                                    \
    int pp_ = k0_ >> 10;                                                    \
    int kk_ = k0_ & 1023;                                                   \
    const unsigned short* As_ = (pp_ == 2) ? xl_b : xh_b;                   \
    const unsigned short* Bs_ = (pp_ == 1) ? xl_b : xh_b;                   \
    load16(As_ + aoff0 + kk_, &As[BUF][cbase0 * 8]);                        \
    load16(As_ + aoff1 + kk_, &As[BUF][cbase1 * 8]);                        \
    load16(Bs_ + boff0 + kk_, &Bs[BUF][cbase0 * 8]);                        \
    load16(Bs_ + boff1 + kk_, &Bs[BUF][cbase1 * 8]);                        \
  }

  f32x4 acc[4][4];
#pragma unroll
  for (int m = 0; m < 4; ++m)
#pragma unroll
    for (int n = 0; n < 4; ++n)
#pragma unroll
      for (int j = 0; j < 4; ++j) acc[m][n][j] = 0.0f;

  STAGE_SC(0, 0);
  STAGE_SC(1, 1);
  STAGE_SC(2, 2);
  int cur = 0;
  for (int kt = 0; kt < NT_SC - 2; ++kt) {
    asm volatile("s_waitcnt vmcnt(8)" ::: "memory");
    __builtin_amdgcn_s_barrier();
    __builtin_amdgcn_sched_barrier(0);
    COMPUTE_TILE(As, Bs, cur);
    __builtin_amdgcn_sched_barrier(0);
    __builtin_amdgcn_s_barrier();
    if (kt + 3 < NT_SC) STAGE_SC(kt + 3, cur);
    cur = (cur == 2) ? 0 : cur + 1;
  }
  asm volatile("s_waitcnt vmcnt(4)" ::: "memory");
  __builtin_amdgcn_s_barrier();
  COMPUTE_TILE(As, Bs, (NT_SC - 2) % 3);
  asm volatile("s_waitcnt vmcnt(0)" ::: "memory");
  __builtin_amdgcn_s_barrier();
  COMPUTE_TILE(As, Bs, (NT_SC - 1) % 3);

#pragma unroll
  for (int m = 0; m < 4; ++m)
#pragma unroll
    for (int n = 0; n < 4; ++n)
#pragma unroll
      for (int j = 0; j < 4; ++j) {
        int r = m0 + wr * 64 + m * 16 + lhi * 4 + j;
        int c = n0 + wc * 64 + n * 16 + l15;
        S_b[(long)r * SEQ + c] = acc[m][n][j];
      }
  if (bm != bn) {
#pragma unroll
    for (int m = 0; m < 4; ++m)
#pragma unroll
      for (int n = 0; n < 4; ++n) {
        int r0 = m0 + wr * 64 + m * 16 + lhi * 4;
        int c = n0 + wc * 64 + n * 16 + l15;
        *(f32x4*)&S_b[(long)c * SEQ + r0] = acc[m][n];
      }
  }
}

// ---------------- K3: masked softmax, wave per row ----------------
__global__ __launch_bounds__(256) void k_softmax(
    const float* __restrict__ S, const int* __restrict__ mask,
    unsigned short* __restrict__ P) {
  int w = threadIdx.x >> 6, lane = threadIdx.x & 63;
  long row = (long)blockIdx.x * 4 + w;
  int b = (int)(row >> 11);
  const float* Sp = S + row * SEQ;
  const int* mp = mask + b * SEQ;
  unsigned short* Pp = P + row * SEQ;

  float sv[32];
  float mx = -__builtin_inff();
#pragma unroll
  for (int ci = 0; ci < 8; ++ci) {
    int col = ci * 256 + lane * 4;
    float4 v = *(const float4*)(Sp + col);
    int4 mk = *(const int4*)(mp + col);
    sv[ci * 4 + 0] = mk.x ? v.x : -__builtin_inff();
    sv[ci * 4 + 1] = mk.y ? v.y : -__builtin_inff();
    sv[ci * 4 + 2] = mk.z ? v.z : -__builtin_inff();
    sv[ci * 4 + 3] = mk.w ? v.w : -__builtin_inff();
    mx = fmaxf(mx, fmaxf(fmaxf(sv[ci * 4 + 0], sv[ci * 4 + 1]),
                         fmaxf(sv[ci * 4 + 2], sv[ci * 4 + 3])));
  }
#pragma unroll
  for (int off = 32; off; off >>= 1) mx = fmaxf(mx, __shfl_xor(mx, off));
  float pv[32];
  float sum = 0.0f;
#pragma unroll
  for (int i = 0; i < 32; ++i) {
    pv[i] = expf(sv[i] - mx);
    sum += pv[i];
  }
#pragma unroll
  for (int off = 32; off; off >>= 1) sum += __shfl_xor(sum, off);
  float inv = 1.0f / sum;
#pragma unroll
  for (int ci = 0; ci < 8; ++ci) {
    int col = ci * 256 + lane * 4;
    *(ushort4*)(Pp + col) = make_ushort4(
        f2bf(pv[ci * 4 + 0] * inv), f2bf(pv[ci * 4 + 1] * inv),
        f2bf(pv[ci * 4 + 2] * inv), f2bf(pv[ci * 4 + 3] * inv));
  }
}

// ---------------- K4: context GEMM 256^2 BK=64, 2 phases/tile ----------------
// LDS: [buf][kk][R][32]; phase = one kk-half, 32 MFMA, PH discipline kept.
// Staging ladder + vmcnt invariants R7-exact: phase A stages kt+1-kk1,
// phase B stages kt+2-kk0; boundary vmcnt(4) drains kt+1's 8 loads.
#define NT_CTX 32
__global__ __launch_bounds__(512, 2) void k_context(
    const unsigned short* __restrict__ P, const unsigned short* __restrict__ xT,
    const float* __restrict__ x, float* __restrict__ out) {
  __shared__ unsigned short As[2 * 16384];  // 64 KB
  __shared__ unsigned short Bs[2 * 16384];  // 64 KB
  int p = blockIdx.x;            // 0..255
  int b = p & 7;                 // one batch per XCD (T1)
  int q = p >> 3;                // 0..31
  int n0 = (q & 3) * 256;        // d cols
  int m0 = (q >> 2) * 256;       // q rows
  const unsigned short* A_b = P + (long)b * SEQ * SEQ;
  const unsigned short* B_b = xT + (long)b * DIM * SEQ;

  int tid = threadIdx.x;
  int w = tid >> 6, lane = tid & 63;
  int wr = w >> 2, wc = w & 3;          // 2M x 4N waves; per-wave 128x64
  int l15 = lane & 15, lhi = lane >> 4;

  int c0 = w * 128 + lane, c1 = w * 128 + 64 + lane;
  int R0 = c0 >> 2, R1 = c1 >> 2;
  int sw0 = ((c0 & 3) ^ ((R0 >> 1) & 3)) * 8;
  int sw1 = ((c1 & 3) ^ ((R1 >> 1) & 3)) * 8;
  const unsigned short* PA0 = A_b + (long)(m0 + R0) * SEQ + sw0;
  const unsigned short* PA1 = A_b + (long)(m0 + R1) * SEQ + sw1;
  const unsigned short* PB0 = B_b + (long)(n0 + R0) * SEQ + sw0;
  const unsigned short* PB1 = B_b + (long)(n0 + R1) * SEQ + sw1;
  int ldg0 = (w * 128) * 8;
  int ldg1 = (w * 128 + 64) * 8;

#define STG_A(KT, KK, BUF)                                              \
  {                                                                     \
    load16(PA0 + (KT) * 64 + (KK) * 32, &As[(BUF)*16384 + (KK)*8192 + ldg0]); \
    load16(PA1 + (KT) * 64 + (KK) * 32, &As[(BUF)*16384 + (KK)*8192 + ldg1]); \
  }
#define STG_B(KT, KK, BUF)                                              \
  {                                                                     \
    load16(PB0 + (KT) * 64 + (KK) * 32, &Bs[(BUF)*16384 + (KK)*8192 + ldg0]); \
    load16(PB1 + (KT) * 64 + (KK) * 32, &Bs[(BUF)*16384 + (KK)*8192 + ldg1]); \
  }

  int swr = (lhi ^ ((l15 >> 1) & 3)) * 8;
  int arow = (wr * 128 + l15) * 32;
  int brow = (wc * 64 + l15) * 32;

  // one kk-half phase: read 12 frags, stage 4 loads, PH discipline, 32 MFMA
#define PHASE_CTX(BUF, KK, DO_STG_A, DO_STG_B, STKT, STKK, STBUF)             \
  {                                                                           \
    bf16x8 af[8], bg[4];                                                      \
    _Pragma("unroll") for (int n = 0; n < 4; ++n)                             \
        bg[n] = *(const bf16x8*)&Bs[(BUF)*16384 + (KK)*8192 + brow + n * 512 + swr]; \
    _Pragma("unroll") for (int m = 0; m < 8; ++m)                             \
        af[m] = *(const bf16x8*)&As[(BUF)*16384 + (KK)*8192 + arow + m * 512 + swr]; \
    if (DO_STG_A) STG_A(STKT, STKK, STBUF);                                   \
    if (DO_STG_B) STG_B(STKT, STKK, STBUF);                                   \
    __builtin_amdgcn_s_barrier();                                             \
    asm volatile("s_waitcnt lgkmcnt(0)" ::: "memory");                        \
    __builtin_amdgcn_sched_barrier(0);                                        \
    __builtin_amdgcn_s_setprio(1);                                            \
    _Pragma("unroll") for (int m = 0; m < 8; ++m)                             \
      _Pragma("unroll") for (int n = 0; n < 4; ++n)                           \
        acc[m][n] = __builtin_amdgcn_mfma_f32_16x16x32_bf16(                  \
            bg[n], af[m], acc[m][n], 0, 0, 0);                                \
    __builtin_amdgcn_s_setprio(0);                                            \
    __builtin_amdgcn_sched_barrier(0);                                        \
  }

  f32x4 acc[8][4];
#pragma unroll
  for (int m = 0; m < 8; ++m)
#pragma unroll
    for (int n = 0; n < 4; ++n)
#pragma unroll
      for (int j = 0; j < 4; ++j) acc[m][n][j] = 0.0f;

  // prologue: kt0 full (8 loads) + kt1 kk0 (4 loads); drain kt0 -> vmcnt(4)
  STG_A(0, 0, 0); STG_B(0, 0, 0);
  STG_A(0, 1, 0); STG_B(0, 1, 0);
  STG_A(1, 0, 1); STG_B(1, 0, 1);
  asm volatile("s_waitcnt vmcnt(4)" ::: "memory");
  __builtin_amdgcn_s_barrier();

  for (int kt = 0; kt < NT_CTX; ++kt) {
    int c = kt & 1, o = c ^ 1;
    int haveN1 = (kt + 1 < NT_CTX), haveN2 = (kt + 2 < NT_CTX);
    // phase A: compute kk0 of c; stage kt+1-kk1 -> o
    PHASE_CTX(c, 0, haveN1, haveN1, kt + 1, 1, o);
    __builtin_amdgcn_s_barrier();   // all waves done reading c-kk0
    // phase B: compute kk1 of c; stage kt+2-kk0 -> c (kk0 region, just released)
    PHASE_CTX(c, 1, haveN2, haveN2, kt + 2, 0, c);
    // boundary: counted wait (drains kt+1's 8 loads), then barrier
    if (kt < NT_CTX - 2) {
      asm volatile("s_waitcnt vmcnt(4)" ::: "memory");
    } else if (kt == NT_CTX - 2) {
      asm volatile("s_waitcnt vmcnt(0)" ::: "memory");
    }
    __builtin_amdgcn_s_barrier();
  }

  // epilogue: swapped-operand C layout -> thread holds 4 consecutive d (f32x4)
  const float* x_b = x + (long)b * SEQ * DIM;
  float* out_b = out + (long)b * SEQ * (5 * DIM);
#pragma unroll
  for (int m = 0; m < 8; ++m)
#pragma unroll
    for (int n = 0; n < 4; ++n) {
      int qi = m0 + wr * 128 + m * 16 + l15;      // col index = q
      int d = n0 + wc * 64 + n * 16 + lhi * 4;    // row index = d (4 consec)
      f32x4 c4 = acc[m][n];
      f32x4 xv = *(const f32x4*)&x_b[(long)qi * DIM + d];
      long base = (long)qi * (5 * DIM) + d;
      *(f32x4*)&out_b[base] = xv;
      *(f32x4*)&out_b[base + DIM] = c4;
      *(f32x4*)&out_b[base + 2 * DIM] = xv + c4;
      *(f32x4*)&out_b[base + 3 * DIM] = xv - c4;
      *(f32x4*)&out_b[base + 4 * DIM] = xv * c4;
    }
}

extern "C" void kernel_launch(void* const* d_in, const int* in_sizes, int n_in,
                              void* d_out, int out_size, void* d_ws, size_t ws_size,
                              hipStream_t stream) {
  const float* x = (const float*)d_in[0];
  const int* mask = (const int*)d_in[1];
  float* out = (float*)d_out;
  char* ws = (char*)d_ws;

  const size_t HB = (size_t)NBATCH * SEQ * DIM * 2;
  unsigned short* xh = (unsigned short*)ws;
  unsigned short* xl = (unsigned short*)(ws + HB);
  unsigned short* xT = (unsigned short*)(ws + 2 * HB);
  unsigned short* P = (unsigned short*)(ws + 3 * HB);
  const size_t PB = (size_t)NBATCH * SEQ * SEQ * 2;
  const size_t SB = (size_t)NBATCH * SEQ * SEQ * 4;
  float* S;
  if (ws_size >= 3 * HB + PB + SB) {
    S = (float*)(ws + 3 * HB + PB);
  } else {
    S = (float*)d_out;  // S dead before K4 writes out
  }

  k_prep<<<dim3(SEQ / 32, DIM / 32, NBATCH), 256, 0, stream>>>(x, xh, xl, xT);
  k_scores<<<dim3(136, 1, NBATCH), 256, 0, stream>>>(xh, xl, S);
  k_softmax<<<NBATCH * SEQ / 4, 256, 0, stream>>>(S, mask, P);
  k_context<<<dim3(256, 1, 1), 512, 0, stream>>>(P, xT, x, out);
}

// Round 11
// 391.250 us; speedup vs baseline: 1.1404x; 1.0232x over previous
//
#include <hip/hip_runtime.h>
#include <hip/hip_bf16.h>

// Biattention: x:[8,2048,1024] f32, mask:[8,2048] i32
// out = concat([x, c, x+c, x-c, x*c], -1) where c = softmax(mask(x x^T)) x
//
// R11: full fp16 path (was bf16): h=fp16(x), l=fp16(x-h) split (22 mantissa
// bits vs 18), S stored FP16 (halves S traffic; exp-arg error <=0.06 at
// masked-row max ~125), P fp16, xT fp16, MFMA f32_16x16x32_f16 (same rate).
// Structure R10-exact: scores = 128^2 d3 compiler-scheduled; context = 256^2
// BK=64 2-phase disciplined; T1 batch-per-XCD; T2 swizzle (0 conflicts).

typedef __attribute__((ext_vector_type(8))) _Float16 half8;
typedef __attribute__((ext_vector_type(8))) unsigned short ushort8;
typedef __attribute__((ext_vector_type(4))) float f32x4;

#define SEQ 2048
#define DIM 1024
#define NBATCH 8
#define BK 32

__device__ __forceinline__ unsigned short f2h(float f) {
  union { _Float16 h; unsigned short u; } cv;
  cv.h = (_Float16)f;
  return cv.u;
}
__device__ __forceinline__ float h2f(unsigned short u) {
  union { _Float16 h; unsigned short u; } cv;
  cv.u = u;
  return (float)cv.h;
}

__device__ __forceinline__ void load16(const void* g, void* l) {
  __builtin_amdgcn_global_load_lds(
      (const __attribute__((address_space(1))) unsigned int*)g,
      (__attribute__((address_space(3))) unsigned int*)l, 16, 0, 0);
}

// ---------------- K1: convert + transpose (fp16) ----------------
__global__ __launch_bounds__(256) void k_prep(
    const float* __restrict__ x, unsigned short* __restrict__ xh,
    unsigned short* __restrict__ xl, unsigned short* __restrict__ xT) {
  __shared__ unsigned short tile[32][33];
  int b = blockIdx.z;
  int s0 = blockIdx.x * 32;
  int d0 = blockIdx.y * 32;
  int t = threadIdx.x;
  int r = t >> 3;
  int c4 = (t & 7) * 4;

  long src = (long)(b * SEQ + s0 + r) * DIM + d0 + c4;
  float4 v = *(const float4*)(x + src);
  float vv[4] = {v.x, v.y, v.z, v.w};
  unsigned short hu[4], lu[4];
#pragma unroll
  for (int j = 0; j < 4; ++j) {
    hu[j] = f2h(vv[j]);
    float hf = h2f(hu[j]);
    lu[j] = f2h(vv[j] - hf);
    tile[r][c4 + j] = hu[j];
  }
  *(ushort4*)(xh + src) = make_ushort4(hu[0], hu[1], hu[2], hu[3]);
  *(ushort4*)(xl + src) = make_ushort4(lu[0], lu[1], lu[2], lu[3]);
  __syncthreads();
  unsigned short tv[4];
#pragma unroll
  for (int j = 0; j < 4; ++j) tv[j] = tile[c4 + j][r];
  long dst = (long)(b * DIM + d0 + r) * SEQ + s0 + c4;
  *(ushort4*)(xT + dst) = make_ushort4(tv[0], tv[1], tv[2], tv[3]);
}

// shared compute macro (R5-exact structure, f16 MFMA)
#define COMPUTE_TILE(ARR_A, ARR_B, BUF)                                     \
  {                                                                         \
    half8 af[4], bg[4];                                                     \
    _Pragma("unroll") for (int m = 0; m < 4; ++m) {                         \
      int R = wr * 64 + m * 16 + l15;                                       \
      af[m] = *(const half8*)&ARR_A[BUF][R * BK + ((lhi ^ ((R >> 1) & 3)) * 8)]; \
    }                                                                       \
    _Pragma("unroll") for (int n = 0; n < 4; ++n) {                         \
      int R = wc * 64 + n * 16 + l15;                                       \
      bg[n] = *(const half8*)&ARR_B[BUF][R * BK + ((lhi ^ ((R >> 1) & 3)) * 8)]; \
    }                                                                       \
    _Pragma("unroll") for (int m = 0; m < 4; ++m)                           \
      _Pragma("unroll") for (int n = 0; n < 4; ++n)                         \
        acc[m][n] = __builtin_amdgcn_mfma_f32_16x16x32_f16(af[m], bg[n], acc[m][n], 0, 0, 0); \
  }

// ---------------- K2: scores GEMM (128^2, split-fp16, symmetric, d3) ----------------
#define NT_SC 96
__global__ __launch_bounds__(256) void k_scores(
    const unsigned short* __restrict__ xh, const unsigned short* __restrict__ xl,
    unsigned short* __restrict__ S) {
  __shared__ unsigned short As[3][128 * BK];
  __shared__ unsigned short Bs[3][128 * BK];
  int p = blockIdx.x + 136 * blockIdx.z;   // 0..1087
  int b = p & 7;                            // one batch per XCD (T1)
  int t = p >> 3;                           // tri-index 0..135
  int bm = 0, rem = 16;
  while (t >= rem) { t -= rem; ++bm; --rem; }
  int bn = bm + t;
  int m0 = bm * 128;
  int n0 = bn * 128;
  const unsigned short* xh_b = xh + (long)b * SEQ * DIM;
  const unsigned short* xl_b = xl + (long)b * SEQ * DIM;
  unsigned short* S_b = S + (long)b * SEQ * SEQ;

  int tid = threadIdx.x;
  int w = tid >> 6, lane = tid & 63;
  int wr = w >> 1, wc = w & 1;
  int l15 = lane & 15, lhi = lane >> 4;

  int cbase0 = w * 64, cbase1 = 256 + w * 64;
  int c0 = cbase0 + lane, c1 = cbase1 + lane;
  int row0 = c0 >> 2, row1 = c1 >> 2;
  long aoff0 = (long)(m0 + row0) * DIM + ((c0 & 3) ^ ((row0 >> 1) & 3)) * 8;
  long aoff1 = (long)(m0 + row1) * DIM + ((c1 & 3) ^ ((row1 >> 1) & 3)) * 8;
  long boff0 = (long)(n0 + row0) * DIM + ((c0 & 3) ^ ((row0 >> 1) & 3)) * 8;
  long boff1 = (long)(n0 + row1) * DIM + ((c1 & 3) ^ ((row1 >> 1) & 3)) * 8;

#define STAGE_SC(KT, BUF)                                                   \
  {                                                                         \
    int k0_ = (KT) * BK;                                                    \
    int pp_ = k0_ >> 10;                                                    \
    int kk_ = k0_ & 1023;                                                   \
    const unsigned short* As_ = (pp_ == 2) ? xl_b : xh_b;                   \
    const unsigned short* Bs_ = (pp_ == 1) ? xl_b : xh_b;                   \
    load16(As_ + aoff0 + kk_, &As[BUF][cbase0 * 8]);                        \
    load16(As_ + aoff1 + kk_, &As[BUF][cbase1 * 8]);                        \
    load16(Bs_ + boff0 + kk_, &Bs[BUF][cbase0 * 8]);                        \
    load16(Bs_ + boff1 + kk_, &Bs[BUF][cbase1 * 8]);                        \
  }

  f32x4 acc[4][4];
#pragma unroll
  for (int m = 0; m < 4; ++m)
#pragma unroll
    for (int n = 0; n < 4; ++n)
#pragma unroll
      for (int j = 0; j < 4; ++j) acc[m][n][j] = 0.0f;

  STAGE_SC(0, 0);
  STAGE_SC(1, 1);
  STAGE_SC(2, 2);
  int cur = 0;
  for (int kt = 0; kt < NT_SC - 2; ++kt) {
    asm volatile("s_waitcnt vmcnt(8)" ::: "memory");
    __builtin_amdgcn_s_barrier();
    __builtin_amdgcn_sched_barrier(0);
    COMPUTE_TILE(As, Bs, cur);
    __builtin_amdgcn_sched_barrier(0);
    __builtin_amdgcn_s_barrier();
    if (kt + 3 < NT_SC) STAGE_SC(kt + 3, cur);
    cur = (cur == 2) ? 0 : cur + 1;
  }
  asm volatile("s_waitcnt vmcnt(4)" ::: "memory");
  __builtin_amdgcn_s_barrier();
  COMPUTE_TILE(As, Bs, (NT_SC - 2) % 3);
  asm volatile("s_waitcnt vmcnt(0)" ::: "memory");
  __builtin_amdgcn_s_barrier();
  COMPUTE_TILE(As, Bs, (NT_SC - 1) % 3);

  // normal-orientation write (scalar fp16)
#pragma unroll
  for (int m = 0; m < 4; ++m)
#pragma unroll
    for (int n = 0; n < 4; ++n)
#pragma unroll
      for (int j = 0; j < 4; ++j) {
        int r = m0 + wr * 64 + m * 16 + lhi * 4 + j;
        int c = n0 + wc * 64 + n * 16 + l15;
        S_b[(long)r * SEQ + c] = f2h(acc[m][n][j]);
      }
  // transposed write for off-diagonal blocks (half4 = 8B)
  if (bm != bn) {
#pragma unroll
    for (int m = 0; m < 4; ++m)
#pragma unroll
      for (int n = 0; n < 4; ++n) {
        int r0 = m0 + wr * 64 + m * 16 + lhi * 4;
        int c = n0 + wc * 64 + n * 16 + l15;
        *(ushort4*)&S_b[(long)c * SEQ + r0] = make_ushort4(
            f2h(acc[m][n][0]), f2h(acc[m][n][1]),
            f2h(acc[m][n][2]), f2h(acc[m][n][3]));
      }
  }
}

// ---------------- K3: masked softmax (fp16 in, fp16 out), wave per row ----------------
__global__ __launch_bounds__(256) void k_softmax(
    const unsigned short* __restrict__ S, const int* __restrict__ mask,
    unsigned short* __restrict__ P) {
  int w = threadIdx.x >> 6, lane = threadIdx.x & 63;
  long row = (long)blockIdx.x * 4 + w;
  int b = (int)(row >> 11);
  const unsigned short* Sp = S + row * SEQ;
  const int* mp = mask + b * SEQ;
  unsigned short* Pp = P + row * SEQ;

  float sv[32];
  float mx = -__builtin_inff();
#pragma unroll
  for (int ci = 0; ci < 4; ++ci) {
    int col = ci * 512 + lane * 8;
    ushort8 v = *(const ushort8*)(Sp + col);
    int4 ma = *(const int4*)(mp + col);
    int4 mb = *(const int4*)(mp + col + 4);
    int mk[8] = {ma.x, ma.y, ma.z, ma.w, mb.x, mb.y, mb.z, mb.w};
#pragma unroll
    for (int j = 0; j < 8; ++j) {
      float s = mk[j] ? h2f(v[j]) : -__builtin_inff();
      sv[ci * 8 + j] = s;
      mx = fmaxf(mx, s);
    }
  }
#pragma unroll
  for (int off = 32; off; off >>= 1) mx = fmaxf(mx, __shfl_xor(mx, off));
  float pv[32];
  float sum = 0.0f;
#pragma unroll
  for (int i = 0; i < 32; ++i) {
    pv[i] = expf(sv[i] - mx);
    sum += pv[i];
  }
#pragma unroll
  for (int off = 32; off; off >>= 1) sum += __shfl_xor(sum, off);
  float inv = 1.0f / sum;
#pragma unroll
  for (int ci = 0; ci < 4; ++ci) {
    int col = ci * 512 + lane * 8;
    ushort8 o;
#pragma unroll
    for (int j = 0; j < 8; ++j) o[j] = f2h(pv[ci * 8 + j] * inv);
    *(ushort8*)(Pp + col) = o;
  }
}

// ---------------- K4: context GEMM 256^2 BK=64, 2 phases/tile (R10-exact, f16) ----------------
#define NT_CTX 32
__global__ __launch_bounds__(512, 2) void k_context(
    const unsigned short* __restrict__ P, const unsigned short* __restrict__ xT,
    const float* __restrict__ x, float* __restrict__ out) {
  __shared__ unsigned short As[2 * 16384];  // 64 KB
  __shared__ unsigned short Bs[2 * 16384];  // 64 KB
  int p = blockIdx.x;            // 0..255
  int b = p & 7;                 // one batch per XCD (T1)
  int q = p >> 3;                // 0..31
  int n0 = (q & 3) * 256;        // d cols
  int m0 = (q >> 2) * 256;       // q rows
  const unsigned short* A_b = P + (long)b * SEQ * SEQ;
  const unsigned short* B_b = xT + (long)b * DIM * SEQ;

  int tid = threadIdx.x;
  int w = tid >> 6, lane = tid & 63;
  int wr = w >> 2, wc = w & 3;          // 2M x 4N waves; per-wave 128x64
  int l15 = lane & 15, lhi = lane >> 4;

  int c0 = w * 128 + lane, c1 = w * 128 + 64 + lane;
  int R0 = c0 >> 2, R1 = c1 >> 2;
  int sw0 = ((c0 & 3) ^ ((R0 >> 1) & 3)) * 8;
  int sw1 = ((c1 & 3) ^ ((R1 >> 1) & 3)) * 8;
  const unsigned short* PA0 = A_b + (long)(m0 + R0) * SEQ + sw0;
  const unsigned short* PA1 = A_b + (long)(m0 + R1) * SEQ + sw1;
  const unsigned short* PB0 = B_b + (long)(n0 + R0) * SEQ + sw0;
  const unsigned short* PB1 = B_b + (long)(n0 + R1) * SEQ + sw1;
  int ldg0 = (w * 128) * 8;
  int ldg1 = (w * 128 + 64) * 8;

#define STG_A(KT, KK, BUF)                                              \
  {                                                                     \
    load16(PA0 + (KT) * 64 + (KK) * 32, &As[(BUF)*16384 + (KK)*8192 + ldg0]); \
    load16(PA1 + (KT) * 64 + (KK) * 32, &As[(BUF)*16384 + (KK)*8192 + ldg1]); \
  }
#define STG_B(KT, KK, BUF)                                              \
  {                                                                     \
    load16(PB0 + (KT) * 64 + (KK) * 32, &Bs[(BUF)*16384 + (KK)*8192 + ldg0]); \
    load16(PB1 + (KT) * 64 + (KK) * 32, &Bs[(BUF)*16384 + (KK)*8192 + ldg1]); \
  }

  int swr = (lhi ^ ((l15 >> 1) & 3)) * 8;
  int arow = (wr * 128 + l15) * 32;
  int brow = (wc * 64 + l15) * 32;

  // one kk-half phase: read 12 frags, stage 4 loads, PH discipline, 32 MFMA
#define PHASE_CTX(BUF, KK, DO_STG_A, DO_STG_B, STKT, STKK, STBUF)             \
  {                                                                           \
    half8 af[8], bg[4];                                                       \
    _Pragma("unroll") for (int n = 0; n < 4; ++n)                             \
        bg[n] = *(const half8*)&Bs[(BUF)*16384 + (KK)*8192 + brow + n * 512 + swr]; \
    _Pragma("unroll") for (int m = 0; m < 8; ++m)                             \
        af[m] = *(const half8*)&As[(BUF)*16384 + (KK)*8192 + arow + m * 512 + swr]; \
    if (DO_STG_A) STG_A(STKT, STKK, STBUF);                                   \
    if (DO_STG_B) STG_B(STKT, STKK, STBUF);                                   \
    __builtin_amdgcn_s_barrier();                                             \
    asm volatile("s_waitcnt lgkmcnt(0)" ::: "memory");                        \
    __builtin_amdgcn_sched_barrier(0);                                        \
    __builtin_amdgcn_s_setprio(1);                                            \
    _Pragma("unroll") for (int m = 0; m < 8; ++m)                             \
      _Pragma("unroll") for (int n = 0; n < 4; ++n)                           \
        acc[m][n] = __builtin_amdgcn_mfma_f32_16x16x32_f16(                   \
            bg[n], af[m], acc[m][n], 0, 0, 0);                                \
    __builtin_amdgcn_s_setprio(0);                                            \
    __builtin_amdgcn_sched_barrier(0);                                        \
  }

  f32x4 acc[8][4];
#pragma unroll
  for (int m = 0; m < 8; ++m)
#pragma unroll
    for (int n = 0; n < 4; ++n)
#pragma unroll
      for (int j = 0; j < 4; ++j) acc[m][n][j] = 0.0f;

  // prologue: kt0 full (8 loads) + kt1 kk0 (4 loads); drain kt0 -> vmcnt(4)
  STG_A(0, 0, 0); STG_B(0, 0, 0);
  STG_A(0, 1, 0); STG_B(0, 1, 0);
  STG_A(1, 0, 1); STG_B(1, 0, 1);
  asm volatile("s_waitcnt vmcnt(4)" ::: "memory");
  __builtin_amdgcn_s_barrier();

  for (int kt = 0; kt < NT_CTX; ++kt) {
    int c = kt & 1, o = c ^ 1;
    int haveN1 = (kt + 1 < NT_CTX), haveN2 = (kt + 2 < NT_CTX);
    // phase A: compute kk0 of c; stage kt+1-kk1 -> o
    PHASE_CTX(c, 0, haveN1, haveN1, kt + 1, 1, o);
    __builtin_amdgcn_s_barrier();   // all waves done reading c-kk0
    // phase B: compute kk1 of c; stage kt+2-kk0 -> c (region just released)
    PHASE_CTX(c, 1, haveN2, haveN2, kt + 2, 0, c);
    if (kt < NT_CTX - 2) {
      asm volatile("s_waitcnt vmcnt(4)" ::: "memory");
    } else if (kt == NT_CTX - 2) {
      asm volatile("s_waitcnt vmcnt(0)" ::: "memory");
    }
    __builtin_amdgcn_s_barrier();
  }

  // epilogue: swapped-operand C layout -> thread holds 4 consecutive d (f32x4)
  const float* x_b = x + (long)b * SEQ * DIM;
  float* out_b = out + (long)b * SEQ * (5 * DIM);
#pragma unroll
  for (int m = 0; m < 8; ++m)
#pragma unroll
    for (int n = 0; n < 4; ++n) {
      int qi = m0 + wr * 128 + m * 16 + l15;      // col index = q
      int d = n0 + wc * 64 + n * 16 + lhi * 4;    // row index = d (4 consec)
      f32x4 c4 = acc[m][n];
      f32x4 xv = *(const f32x4*)&x_b[(long)qi * DIM + d];
      long base = (long)qi * (5 * DIM) + d;
      *(f32x4*)&out_b[base] = xv;
      *(f32x4*)&out_b[base + DIM] = c4;
      *(f32x4*)&out_b[base + 2 * DIM] = xv + c4;
      *(f32x4*)&out_b[base + 3 * DIM] = xv - c4;
      *(f32x4*)&out_b[base + 4 * DIM] = xv * c4;
    }
}

extern "C" void kernel_launch(void* const* d_in, const int* in_sizes, int n_in,
                              void* d_out, int out_size, void* d_ws, size_t ws_size,
                              hipStream_t stream) {
  const float* x = (const float*)d_in[0];
  const int* mask = (const int*)d_in[1];
  float* out = (float*)d_out;
  char* ws = (char*)d_ws;

  const size_t HB = (size_t)NBATCH * SEQ * DIM * 2;
  unsigned short* xh = (unsigned short*)ws;
  unsigned short* xl = (unsigned short*)(ws + HB);
  unsigned short* xT = (unsigned short*)(ws + 2 * HB);
  unsigned short* P = (unsigned short*)(ws + 3 * HB);
  const size_t PB = (size_t)NBATCH * SEQ * SEQ * 2;
  const size_t SB = (size_t)NBATCH * SEQ * SEQ * 2;   // S now fp16
  unsigned short* S;
  if (ws_size >= 3 * HB + PB + SB) {
    S = (unsigned short*)(ws + 3 * HB + PB);
  } else {
    S = (unsigned short*)d_out;  // S dead before K4 writes out
  }

  k_prep<<<dim3(SEQ / 32, DIM / 32, NBATCH), 256, 0, stream>>>(x, xh, xl, xT);
  k_scores<<<dim3(136, 1, NBATCH), 256, 0, stream>>>(xh, xl, S);
  k_softmax<<<NBATCH * SEQ / 4, 256, 0, stream>>>(S, mask, P);
  k_context<<<dim3(256, 1, 1), 512, 0, stream>>>(P, xT, x, out);
}

// Round 12
// 355.005 us; speedup vs baseline: 1.2568x; 1.1021x over previous
//
#include <hip/hip_runtime.h>
#include <hip/hip_bf16.h>

// Biattention: x:[8,2048,1024] f32, mask:[8,2048] i32
// out = concat([x, c, x+c, x-c, x*c], -1) where c = softmax(mask(x x^T)) x
//
// R12: symmetrized 2-pass scores. With h=fp16(x), l=fp16(x-h), e=fp16(h+2l):
//   S = (h e^T + e h^T)/2 = h h^T + h l^T + l h^T + O(u|x|^2)
// -> K=2048 (2 passes) instead of 3072 (3 passes). Formula is exactly
// symmetric, so triangular-block + mirror write unchanged; diagonal needs no
// special case. Scale acc by 0.5 at write. Rest is R11-exact: fp16 S/P,
// scores = 128^2 d3 compiler-scheduled, context = 256^2 BK=64 2-phase
// disciplined, T1 batch-per-XCD, T2 swizzle (verified 0 conflicts).

typedef __attribute__((ext_vector_type(8))) _Float16 half8;
typedef __attribute__((ext_vector_type(8))) unsigned short ushort8;
typedef __attribute__((ext_vector_type(4))) float f32x4;

#define SEQ 2048
#define DIM 1024
#define NBATCH 8
#define BK 32

__device__ __forceinline__ unsigned short f2h(float f) {
  union { _Float16 h; unsigned short u; } cv;
  cv.h = (_Float16)f;
  return cv.u;
}
__device__ __forceinline__ float h2f(unsigned short u) {
  union { _Float16 h; unsigned short u; } cv;
  cv.u = u;
  return (float)cv.h;
}

__device__ __forceinline__ void load16(const void* g, void* l) {
  __builtin_amdgcn_global_load_lds(
      (const __attribute__((address_space(1))) unsigned int*)g,
      (__attribute__((address_space(3))) unsigned int*)l, 16, 0, 0);
}

// ---------------- K1: convert + transpose (fp16; emits h, e, hT) ----------------
__global__ __launch_bounds__(256) void k_prep(
    const float* __restrict__ x, unsigned short* __restrict__ xh,
    unsigned short* __restrict__ xe, unsigned short* __restrict__ xT) {
  __shared__ unsigned short tile[32][33];
  int b = blockIdx.z;
  int s0 = blockIdx.x * 32;
  int d0 = blockIdx.y * 32;
  int t = threadIdx.x;
  int r = t >> 3;
  int c4 = (t & 7) * 4;

  long src = (long)(b * SEQ + s0 + r) * DIM + d0 + c4;
  float4 v = *(const float4*)(x + src);
  float vv[4] = {v.x, v.y, v.z, v.w};
  unsigned short hu[4], eu[4];
#pragma unroll
  for (int j = 0; j < 4; ++j) {
    hu[j] = f2h(vv[j]);
    float hf = h2f(hu[j]);
    float lf = h2f(f2h(vv[j] - hf));
    eu[j] = f2h(hf + 2.0f * lf);   // e = fp16(h + 2l)
    tile[r][c4 + j] = hu[j];
  }
  *(ushort4*)(xh + src) = make_ushort4(hu[0], hu[1], hu[2], hu[3]);
  *(ushort4*)(xe + src) = make_ushort4(eu[0], eu[1], eu[2], eu[3]);
  __syncthreads();
  unsigned short tv[4];
#pragma unroll
  for (int j = 0; j < 4; ++j) tv[j] = tile[c4 + j][r];
  long dst = (long)(b * DIM + d0 + r) * SEQ + s0 + c4;
  *(ushort4*)(xT + dst) = make_ushort4(tv[0], tv[1], tv[2], tv[3]);
}

// shared compute macro (R5-exact structure, f16 MFMA)
#define COMPUTE_TILE(ARR_A, ARR_B, BUF)                                     \
  {                                                                         \
    half8 af[4], bg[4];                                                     \
    _Pragma("unroll") for (int m = 0; m < 4; ++m) {                         \
      int R = wr * 64 + m * 16 + l15;                                       \
      af[m] = *(const half8*)&ARR_A[BUF][R * BK + ((lhi ^ ((R >> 1) & 3)) * 8)]; \
    }                                                                       \
    _Pragma("unroll") for (int n = 0; n < 4; ++n) {                         \
      int R = wc * 64 + n * 16 + l15;                                       \
      bg[n] = *(const half8*)&ARR_B[BUF][R * BK + ((lhi ^ ((R >> 1) & 3)) * 8)]; \
    }                                                                       \
    _Pragma("unroll") for (int m = 0; m < 4; ++m)                           \
      _Pragma("unroll") for (int n = 0; n < 4; ++n)                         \
        acc[m][n] = __builtin_amdgcn_mfma_f32_16x16x32_f16(af[m], bg[n], acc[m][n], 0, 0, 0); \
  }

// ---------------- K2: scores GEMM (128^2, symmetrized 2-pass, d3) ----------------
// pass 0 (tiles 0..31):  A = h rows(m), B = e rows(n)
// pass 1 (tiles 32..63): A = e rows(m), B = h rows(n)
// S = 0.5 * acc
#define NT_SC 64
__global__ __launch_bounds__(256) void k_scores(
    const unsigned short* __restrict__ xh, const unsigned short* __restrict__ xe,
    unsigned short* __restrict__ S) {
  __shared__ unsigned short As[3][128 * BK];
  __shared__ unsigned short Bs[3][128 * BK];
  int p = blockIdx.x + 136 * blockIdx.z;   // 0..1087
  int b = p & 7;                            // one batch per XCD (T1)
  int t = p >> 3;                           // tri-index 0..135
  int bm = 0, rem = 16;
  while (t >= rem) { t -= rem; ++bm; --rem; }
  int bn = bm + t;
  int m0 = bm * 128;
  int n0 = bn * 128;
  const unsigned short* xh_b = xh + (long)b * SEQ * DIM;
  const unsigned short* xe_b = xe + (long)b * SEQ * DIM;
  unsigned short* S_b = S + (long)b * SEQ * SEQ;

  int tid = threadIdx.x;
  int w = tid >> 6, lane = tid & 63;
  int wr = w >> 1, wc = w & 1;
  int l15 = lane & 15, lhi = lane >> 4;

  int cbase0 = w * 64, cbase1 = 256 + w * 64;
  int c0 = cbase0 + lane, c1 = cbase1 + lane;
  int row0 = c0 >> 2, row1 = c1 >> 2;
  long aoff0 = (long)(m0 + row0) * DIM + ((c0 & 3) ^ ((row0 >> 1) & 3)) * 8;
  long aoff1 = (long)(m0 + row1) * DIM + ((c1 & 3) ^ ((row1 >> 1) & 3)) * 8;
  long boff0 = (long)(n0 + row0) * DIM + ((c0 & 3) ^ ((row0 >> 1) & 3)) * 8;
  long boff1 = (long)(n0 + row1) * DIM + ((c1 & 3) ^ ((row1 >> 1) & 3)) * 8;

#define STAGE_SC(KT, BUF)                                                   \
  {                                                                         \
    int pp_ = (KT) >> 5;                 /* 0: A=h,B=e   1: A=e,B=h */      \
    int kk_ = ((KT) & 31) * BK;                                             \
    const unsigned short* As_ = pp_ ? xe_b : xh_b;                          \
    const unsigned short* Bs_ = pp_ ? xh_b : xe_b;                          \
    load16(As_ + aoff0 + kk_, &As[BUF][cbase0 * 8]);                        \
    load16(As_ + aoff1 + kk_, &As[BUF][cbase1 * 8]);                        \
    load16(Bs_ + boff0 + kk_, &Bs[BUF][cbase0 * 8]);                        \
    load16(Bs_ + boff1 + kk_, &Bs[BUF][cbase1 * 8]);                        \
  }

  f32x4 acc[4][4];
#pragma unroll
  for (int m = 0; m < 4; ++m)
#pragma unroll
    for (int n = 0; n < 4; ++n)
#pragma unroll
      for (int j = 0; j < 4; ++j) acc[m][n][j] = 0.0f;

  STAGE_SC(0, 0);
  STAGE_SC(1, 1);
  STAGE_SC(2, 2);
  int cur = 0;
  for (int kt = 0; kt < NT_SC - 2; ++kt) {
    asm volatile("s_waitcnt vmcnt(8)" ::: "memory");
    __builtin_amdgcn_s_barrier();
    __builtin_amdgcn_sched_barrier(0);
    COMPUTE_TILE(As, Bs, cur);
    __builtin_amdgcn_sched_barrier(0);
    __builtin_amdgcn_s_barrier();
    if (kt + 3 < NT_SC) STAGE_SC(kt + 3, cur);
    cur = (cur == 2) ? 0 : cur + 1;
  }
  asm volatile("s_waitcnt vmcnt(4)" ::: "memory");
  __builtin_amdgcn_s_barrier();
  COMPUTE_TILE(As, Bs, (NT_SC - 2) % 3);
  asm volatile("s_waitcnt vmcnt(0)" ::: "memory");
  __builtin_amdgcn_s_barrier();
  COMPUTE_TILE(As, Bs, (NT_SC - 1) % 3);

  // normal-orientation write (scalar fp16), S = 0.5 * acc
#pragma unroll
  for (int m = 0; m < 4; ++m)
#pragma unroll
    for (int n = 0; n < 4; ++n)
#pragma unroll
      for (int j = 0; j < 4; ++j) {
        int r = m0 + wr * 64 + m * 16 + lhi * 4 + j;
        int c = n0 + wc * 64 + n * 16 + l15;
        S_b[(long)r * SEQ + c] = f2h(0.5f * acc[m][n][j]);
      }
  // transposed write for off-diagonal blocks
  if (bm != bn) {
#pragma unroll
    for (int m = 0; m < 4; ++m)
#pragma unroll
      for (int n = 0; n < 4; ++n) {
        int r0 = m0 + wr * 64 + m * 16 + lhi * 4;
        int c = n0 + wc * 64 + n * 16 + l15;
        *(ushort4*)&S_b[(long)c * SEQ + r0] = make_ushort4(
            f2h(0.5f * acc[m][n][0]), f2h(0.5f * acc[m][n][1]),
            f2h(0.5f * acc[m][n][2]), f2h(0.5f * acc[m][n][3]));
      }
  }
}

// ---------------- K3: masked softmax (fp16 in, fp16 out), wave per row ----------------
__global__ __launch_bounds__(256) void k_softmax(
    const unsigned short* __restrict__ S, const int* __restrict__ mask,
    unsigned short* __restrict__ P) {
  int w = threadIdx.x >> 6, lane = threadIdx.x & 63;
  long row = (long)blockIdx.x * 4 + w;
  int b = (int)(row >> 11);
  const unsigned short* Sp = S + row * SEQ;
  const int* mp = mask + b * SEQ;
  unsigned short* Pp = P + row * SEQ;

  float sv[32];
  float mx = -__builtin_inff();
#pragma unroll
  for (int ci = 0; ci < 4; ++ci) {
    int col = ci * 512 + lane * 8;
    ushort8 v = *(const ushort8*)(Sp + col);
    int4 ma = *(const int4*)(mp + col);
    int4 mb = *(const int4*)(mp + col + 4);
    int mk[8] = {ma.x, ma.y, ma.z, ma.w, mb.x, mb.y, mb.z, mb.w};
#pragma unroll
    for (int j = 0; j < 8; ++j) {
      float s = mk[j] ? h2f(v[j]) : -__builtin_inff();
      sv[ci * 8 + j] = s;
      mx = fmaxf(mx, s);
    }
  }
#pragma unroll
  for (int off = 32; off; off >>= 1) mx = fmaxf(mx, __shfl_xor(mx, off));
  float pv[32];
  float sum = 0.0f;
#pragma unroll
  for (int i = 0; i < 32; ++i) {
    pv[i] = expf(sv[i] - mx);
    sum += pv[i];
  }
#pragma unroll
  for (int off = 32; off; off >>= 1) sum += __shfl_xor(sum, off);
  float inv = 1.0f / sum;
#pragma unroll
  for (int ci = 0; ci < 4; ++ci) {
    int col = ci * 512 + lane * 8;
    ushort8 o;
#pragma unroll
    for (int j = 0; j < 8; ++j) o[j] = f2h(pv[ci * 8 + j] * inv);
    *(ushort8*)(Pp + col) = o;
  }
}

// ---------------- K4: context GEMM 256^2 BK=64, 2 phases/tile (R10-exact, f16) ----------------
#define NT_CTX 32
__global__ __launch_bounds__(512, 2) void k_context(
    const unsigned short* __restrict__ P, const unsigned short* __restrict__ xT,
    const float* __restrict__ x, float* __restrict__ out) {
  __shared__ unsigned short As[2 * 16384];  // 64 KB
  __shared__ unsigned short Bs[2 * 16384];  // 64 KB
  int p = blockIdx.x;            // 0..255
  int b = p & 7;                 // one batch per XCD (T1)
  int q = p >> 3;                // 0..31
  int n0 = (q & 3) * 256;        // d cols
  int m0 = (q >> 2) * 256;       // q rows
  const unsigned short* A_b = P + (long)b * SEQ * SEQ;
  const unsigned short* B_b = xT + (long)b * DIM * SEQ;

  int tid = threadIdx.x;
  int w = tid >> 6, lane = tid & 63;
  int wr = w >> 2, wc = w & 3;          // 2M x 4N waves; per-wave 128x64
  int l15 = lane & 15, lhi = lane >> 4;

  int c0 = w * 128 + lane, c1 = w * 128 + 64 + lane;
  int R0 = c0 >> 2, R1 = c1 >> 2;
  int sw0 = ((c0 & 3) ^ ((R0 >> 1) & 3)) * 8;
  int sw1 = ((c1 & 3) ^ ((R1 >> 1) & 3)) * 8;
  const unsigned short* PA0 = A_b + (long)(m0 + R0) * SEQ + sw0;
  const unsigned short* PA1 = A_b + (long)(m0 + R1) * SEQ + sw1;
  const unsigned short* PB0 = B_b + (long)(n0 + R0) * SEQ + sw0;
  const unsigned short* PB1 = B_b + (long)(n0 + R1) * SEQ + sw1;
  int ldg0 = (w * 128) * 8;
  int ldg1 = (w * 128 + 64) * 8;

#define STG_A(KT, KK, BUF)                                              \
  {                                                                     \
    load16(PA0 + (KT) * 64 + (KK) * 32, &As[(BUF)*16384 + (KK)*8192 + ldg0]); \
    load16(PA1 + (KT) * 64 + (KK) * 32, &As[(BUF)*16384 + (KK)*8192 + ldg1]); \
  }
#define STG_B(KT, KK, BUF)                                              \
  {                                                                     \
    load16(PB0 + (KT) * 64 + (KK) * 32, &Bs[(BUF)*16384 + (KK)*8192 + ldg0]); \
    load16(PB1 + (KT) * 64 + (KK) * 32, &Bs[(BUF)*16384 + (KK)*8192 + ldg1]); \
  }

  int swr = (lhi ^ ((l15 >> 1) & 3)) * 8;
  int arow = (wr * 128 + l15) * 32;
  int brow = (wc * 64 + l15) * 32;

  // one kk-half phase: read 12 frags, stage 4 loads, PH discipline, 32 MFMA
#define PHASE_CTX(BUF, KK, DO_STG_A, DO_STG_B, STKT, STKK, STBUF)             \
  {                                                                           \
    half8 af[8], bg[4];                                                       \
    _Pragma("unroll") for (int n = 0; n < 4; ++n)                             \
        bg[n] = *(const half8*)&Bs[(BUF)*16384 + (KK)*8192 + brow + n * 512 + swr]; \
    _Pragma("unroll") for (int m = 0; m < 8; ++m)                             \
        af[m] = *(const half8*)&As[(BUF)*16384 + (KK)*8192 + arow + m * 512 + swr]; \
    if (DO_STG_A) STG_A(STKT, STKK, STBUF);                                   \
    if (DO_STG_B) STG_B(STKT, STKK, STBUF);                                   \
    __builtin_amdgcn_s_barrier();                                             \
    asm volatile("s_waitcnt lgkmcnt(0)" ::: "memory");                        \
    __builtin_amdgcn_sched_barrier(0);                                        \
    __builtin_amdgcn_s_setprio(1);                                            \
    _Pragma("unroll") for (int m = 0; m < 8; ++m)                             \
      _Pragma("unroll") for (int n = 0; n < 4; ++n)                           \
        acc[m][n] = __builtin_amdgcn_mfma_f32_16x16x32_f16(                   \
            bg[n], af[m], acc[m][n], 0, 0, 0);                                \
    __builtin_amdgcn_s_setprio(0);                                            \
    __builtin_amdgcn_sched_barrier(0);                                        \
  }

  f32x4 acc[8][4];
#pragma unroll
  for (int m = 0; m < 8; ++m)
#pragma unroll
    for (int n = 0; n < 4; ++n)
#pragma unroll
      for (int j = 0; j < 4; ++j) acc[m][n][j] = 0.0f;

  // prologue: kt0 full (8 loads) + kt1 kk0 (4 loads); drain kt0 -> vmcnt(4)
  STG_A(0, 0, 0); STG_B(0, 0, 0);
  STG_A(0, 1, 0); STG_B(0, 1, 0);
  STG_A(1, 0, 1); STG_B(1, 0, 1);
  asm volatile("s_waitcnt vmcnt(4)" ::: "memory");
  __builtin_amdgcn_s_barrier();

  for (int kt = 0; kt < NT_CTX; ++kt) {
    int c = kt & 1, o = c ^ 1;
    int haveN1 = (kt + 1 < NT_CTX), haveN2 = (kt + 2 < NT_CTX);
    // phase A: compute kk0 of c; stage kt+1-kk1 -> o
    PHASE_CTX(c, 0, haveN1, haveN1, kt + 1, 1, o);
    __builtin_amdgcn_s_barrier();   // all waves done reading c-kk0
    // phase B: compute kk1 of c; stage kt+2-kk0 -> c (region just released)
    PHASE_CTX(c, 1, haveN2, haveN2, kt + 2, 0, c);
    if (kt < NT_CTX - 2) {
      asm volatile("s_waitcnt vmcnt(4)" ::: "memory");
    } else if (kt == NT_CTX - 2) {
      asm volatile("s_waitcnt vmcnt(0)" ::: "memory");
    }
    __builtin_amdgcn_s_barrier();
  }

  // epilogue: swapped-operand C layout -> thread holds 4 consecutive d (f32x4)
  const float* x_b = x + (long)b * SEQ * DIM;
  float* out_b = out + (long)b * SEQ * (5 * DIM);
#pragma unroll
  for (int m = 0; m < 8; ++m)
#pragma unroll
    for (int n = 0; n < 4; ++n) {
      int qi = m0 + wr * 128 + m * 16 + l15;      // col index = q
      int d = n0 + wc * 64 + n * 16 + lhi * 4;    // row index = d (4 consec)
      f32x4 c4 = acc[m][n];
      f32x4 xv = *(const f32x4*)&x_b[(long)qi * DIM + d];
      long base = (long)qi * (5 * DIM) + d;
      *(f32x4*)&out_b[base] = xv;
      *(f32x4*)&out_b[base + DIM] = c4;
      *(f32x4*)&out_b[base + 2 * DIM] = xv + c4;
      *(f32x4*)&out_b[base + 3 * DIM] = xv - c4;
      *(f32x4*)&out_b[base + 4 * DIM] = xv * c4;
    }
}

extern "C" void kernel_launch(void* const* d_in, const int* in_sizes, int n_in,
                              void* d_out, int out_size, void* d_ws, size_t ws_size,
                              hipStream_t stream) {
  const float* x = (const float*)d_in[0];
  const int* mask = (const int*)d_in[1];
  float* out = (float*)d_out;
  char* ws = (char*)d_ws;

  const size_t HB = (size_t)NBATCH * SEQ * DIM * 2;
  unsigned short* xh = (unsigned short*)ws;
  unsigned short* xe = (unsigned short*)(ws + HB);
  unsigned short* xT = (unsigned short*)(ws + 2 * HB);
  unsigned short* P = (unsigned short*)(ws + 3 * HB);
  const size_t PB = (size_t)NBATCH * SEQ * SEQ * 2;
  const size_t SB = (size_t)NBATCH * SEQ * SEQ * 2;   // S fp16
  unsigned short* S;
  if (ws_size >= 3 * HB + PB + SB) {
    S = (unsigned short*)(ws + 3 * HB + PB);
  } else {
    S = (unsigned short*)d_out;  // S dead before K4 writes out
  }

  k_prep<<<dim3(SEQ / 32, DIM / 32, NBATCH), 256, 0, stream>>>(x, xh, xe, xT);
  k_scores<<<dim3(136, 1, NBATCH), 256, 0, stream>>>(xh, xe, S);
  k_softmax<<<NBATCH * SEQ / 4, 256, 0, stream>>>(S, mask, P);
  k_context<<<dim3(256, 1, 1), 512, 0, stream>>>(P, xT, x, out);
}